// Round 22
// baseline (653.843 us; speedup 1.0000x reference)
//
#include <hip/hip_runtime.h>

// AGLI_5703716569604 — round 21: att_gemm computes both orientations per
// thread -> emits att, attT, att2bf AND all 3 stat partial sets register-only;
// tri_stats deleted. Rest = round 20.
// B=2, ch1=64, ch2=128, H=W=64, N=4096, att [B,4096,4096].

#define LB __launch_bounds__(256)

constexpr float BN_SCALE = 0.99999500003749968f; // 1/sqrt(1+1e-5)
constexpr float NEG_BIG  = -3.402823466e38f;
constexpr float LOG2E    = 1.4426950408889634f;
constexpr float LN2      = 0.6931471805599453f;

typedef __attribute__((ext_vector_type(8))) short short8v;
typedef __attribute__((ext_vector_type(4))) float f32x4;

__device__ __forceinline__ ushort bf16rne(float f) {
    unsigned u = __float_as_uint(f);
    unsigned r = (u + 0x7FFFu + ((u >> 16) & 1u)) >> 16;
    return (ushort)r;
}
__device__ __forceinline__ float bf2f(ushort u) {
    return __uint_as_float((unsigned)u << 16);
}

__device__ __forceinline__ void online_merge(float& mx, float& sm, float m2, float s2) {
    const float mn = fmaxf(mx, m2);
    sm = sm * __expf(mx - mn) + s2 * __expf(m2 - mn);
    mx = mn;
}

// ---------------------------------------------------------------------------
// Transpose + bf16: in f32 [B][C][HW] -> outT bf16 [B][HW][C].
__global__ LB void transpose_bf(const float* __restrict__ in, ushort* __restrict__ outT,
                                int C, int HW)
{
    __shared__ float t[32][33];
    const int tid = threadIdx.x;
    const int tx = tid & 31, ty0 = tid >> 5;
    const int hw0 = blockIdx.x * 32, c0 = blockIdx.y * 32, b = blockIdx.z;
    #pragma unroll
    for (int i = 0; i < 4; ++i)
        t[ty0 + i * 8][tx] = in[((long)b * C + c0 + ty0 + i * 8) * HW + hw0 + tx];
    __syncthreads();
    #pragma unroll
    for (int i = 0; i < 4; ++i)
        outT[((long)b * HW + hw0 + ty0 + i * 8) * C + c0 + tx] =
            bf16rne(t[tx][ty0 + i * 8]);
}

// ---------------------------------------------------------------------------
// MFMA direct 3x3 conv (round-18, unchanged).
template<int HASG, int OCB>
__global__ LB void conv3x3_mfma(
    const ushort* __restrict__ inT,
    const float* __restrict__ gconst,
    const float* __restrict__ w,
    const float* __restrict__ bias,
    const float* __restrict__ bn,
    const float* __restrict__ residual,
    float* __restrict__ out,
    ushort* __restrict__ outbf,
    ushort* __restrict__ outTbf,
    int Cg, int Cin, int Cout)
{
    constexpr int TILES = OCB / 16;
    constexpr int TPO = 256 / OCB;
    constexpr int J = 288 / TPO;
    __shared__ ushort ldsA[9][OCB][36];
    __shared__ float wg[OCB][10];
    const int tid = threadIdx.x;
    const int wv = tid >> 6, lane = tid & 63;
    const int fr = lane & 15, fg = lane >> 4;
    const int px0 = blockIdx.x * 64, ocb = blockIdx.y * OCB, b = blockIdx.z;
    const int Ct = Cg + Cin;
    const int p = px0 + wv * 16 + fr;
    const int y = p >> 6, x = p & 63;

    if (HASG) {
        for (int e = tid; e < OCB * 9; e += 256) {
            const int oc = e / 9, k = e % 9;
            float s = 0.f;
            for (int ic = 0; ic < Cg; ++ic)
                s += gconst[b * Cg + ic] * w[((long)(ocb + oc) * Ct + ic) * 9 + k];
            wg[oc][k] = s;
        }
    }

    int qv[9]; bool val[9];
    #pragma unroll
    for (int k = 0; k < 9; ++k) {
        const int yy = y + k / 3 - 1, xx = x + k % 3 - 1;
        val[k] = ((unsigned)yy < 64u) && ((unsigned)xx < 64u);
        qv[k] = val[k] ? (yy * 64 + xx) : 0;
    }

    f32x4 acc[TILES];
    #pragma unroll
    for (int t = 0; t < TILES; ++t) acc[t] = (f32x4){0.f, 0.f, 0.f, 0.f};
    const short8v bz = (short8v){0, 0, 0, 0, 0, 0, 0, 0};

    const int oc_st = tid / TPO, q = tid % TPO;
    const int base_ic = q * (J / 9);
    const ushort* inTb = inT + (long)b * 4096 * Cin + 8 * fg;

    const int NCH = Cin / 32;
    for (int c = 0; c < NCH; ++c) {
        __syncthreads();
        {
            const float* wp = w + (long)(ocb + oc_st) * Ct * 9
                              + (long)(Cg + c * 32) * 9 + q * J;
            #pragma unroll
            for (int j4 = 0; j4 < J; j4 += 4) {
                const float4 v4 = *(const float4*)&wp[j4];
                ldsA[(j4 + 0) % 9][oc_st][base_ic + (j4 + 0) / 9] = bf16rne(v4.x);
                ldsA[(j4 + 1) % 9][oc_st][base_ic + (j4 + 1) / 9] = bf16rne(v4.y);
                ldsA[(j4 + 2) % 9][oc_st][base_ic + (j4 + 2) / 9] = bf16rne(v4.z);
                ldsA[(j4 + 3) % 9][oc_st][base_ic + (j4 + 3) / 9] = bf16rne(v4.w);
            }
        }
        __syncthreads();
        const ushort* inc = inTb + c * 32;
        #pragma unroll
        for (int k = 0; k < 9; ++k) {
            const short8v bfrag = val[k] ? *(const short8v*)&inc[(long)qv[k] * Cin] : bz;
            #pragma unroll
            for (int t = 0; t < TILES; ++t) {
                const short8v afrag = *(const short8v*)&ldsA[k][t * 16 + fr][8 * fg];
                acc[t] = __builtin_amdgcn_mfma_f32_16x16x32_bf16(afrag, bfrag, acc[t], 0, 0, 0);
            }
        }
    }

    #pragma unroll
    for (int t = 0; t < TILES; ++t) {
        float v4[4];
        #pragma unroll
        for (int r = 0; r < 4; ++r) {
            const int ocl = t * 16 + fg * 4 + r;
            const int oc = ocb + ocl;
            float v = acc[t][r];
            if (bias) v += bias[oc];
            if (HASG) {
                #pragma unroll
                for (int k = 0; k < 9; ++k)
                    if (val[k]) v += wg[ocl][k];
            }
            v = fmaxf(fmaf(v, bn[oc] * BN_SCALE, bn[Cout + oc]), 0.f);
            const long oidx = ((long)(b * Cout + oc)) * 4096 + p;
            if (residual) v += residual[oidx];
            out[oidx] = v;
            if (outbf) outbf[oidx] = bf16rne(v);
            v4[r] = v;
        }
        if (outTbf) {
            ushort4 o;
            o.x = bf16rne(v4[0]); o.y = bf16rne(v4[1]);
            o.z = bf16rne(v4[2]); o.w = bf16rne(v4[3]);
            *(ushort4*)&outTbf[((long)(b * 4096 + p)) * Cout + ocb + t * 16 + fg * 4] = o;
        }
    }
}

// ---------------------------------------------------------------------------
__global__ LB void gap_kernel(const float* __restrict__ in,
                              float* __restrict__ o1, float* __restrict__ o2,
                              int C, int HW)
{
    const int c = blockIdx.x, b = blockIdx.y;
    const float* p = in + ((long)b * C + c) * HW;
    float s = 0.f;
    for (int i = threadIdx.x; i < HW; i += 256) s += p[i];
    #pragma unroll
    for (int off = 32; off; off >>= 1) s += __shfl_down(s, off);
    __shared__ float red[4];
    if ((threadIdx.x & 63) == 0) red[threadIdx.x >> 6] = s;
    __syncthreads();
    if (threadIdx.x == 0) {
        const float t = (red[0] + red[1] + red[2] + red[3]) / (float)HW;
        o1[b * C + c] = t;
        o2[b * C + c] = t;
    }
}

// ---------------------------------------------------------------------------
// Doubled att GEMM: accA[nn]=att[n0+nn][m], accB[nn]=att[m][n0+nn].
// Emits att (f32 col-store), attT (f32 row-store), att2bf (bf16 row-store),
// and all 3 stat partial sets [B,128,N] via REGISTER-ONLY reductions.
// grid: (16 m-chunks, 128 n-chunks, B), block 256.
__global__ LB void att_gemm2(const float* __restrict__ fs, const float* __restrict__ fc,
                             float* __restrict__ att, float* __restrict__ attT,
                             ushort* __restrict__ att2bf,
                             float* __restrict__ McP, float* __restrict__ ScP,
                             float* __restrict__ MrP, float* __restrict__ SrP,
                             float* __restrict__ M2P, float* __restrict__ S2P, int N)
{
    __shared__ float lfs[32][33], lfc[32][33];
    const int tid = threadIdx.x;
    const int m  = blockIdx.x * 256 + tid;
    const int j  = blockIdx.y;          // n-chunk 0..127
    const int n0 = j * 32;
    const int b  = blockIdx.z;
    for (int i = tid; i < 1024; i += 256) {
        const int c = i >> 5, nn = i & 31;
        lfs[c][nn] = fs[((long)b * 32 + c) * N + n0 + nn];
        lfc[c][nn] = fc[((long)b * 32 + c) * N + n0 + nn];
    }
    __syncthreads();
    float accA[32], accB[32];
    #pragma unroll
    for (int i = 0; i < 32; ++i) { accA[i] = 0.f; accB[i] = 0.f; }
    const float* fcp = fc + (long)b * 32 * N + m;
    const float* fsp = fs + (long)b * 32 * N + m;
    #pragma unroll
    for (int c = 0; c < 32; ++c) {
        const float vc = fcp[(long)c * N];
        const float vs = fsp[(long)c * N];
        #pragma unroll
        for (int nn = 0; nn < 32; ++nn) {
            accA[nn] = fmaf(lfs[c][nn], vc, accA[nn]);
            accB[nn] = fmaf(lfc[c][nn], vs, accB[nn]);
        }
    }
    // att: rows n0..n0+31 at col m (coalesced col-store)
    float* op = att + ((long)b * N + n0) * N + m;
    #pragma unroll
    for (int nn = 0; nn < 32; ++nn) op[(long)nn * N] = accA[nn];
    // attT: row m cols n0..n0+31 (contiguous row-store)
    float* opT = attT + ((long)b * N + m) * N + n0;
    #pragma unroll
    for (int q = 0; q < 8; ++q)
        *(float4*)&opT[q * 4] = make_float4(accA[q*4], accA[q*4+1], accA[q*4+2], accA[q*4+3]);
    // att2 (symmetric): att2[m][n0+nn] = accA[nn]+accB[nn] (bf16 row-store)
    ushort* o2 = att2bf + ((long)b * N + m) * N + n0;
    #pragma unroll
    for (int q = 0; q < 8; ++q) {
        ushort4 u;
        u.x = bf16rne(accA[q*4+0] + accB[q*4+0]);
        u.y = bf16rne(accA[q*4+1] + accB[q*4+1]);
        u.z = bf16rne(accA[q*4+2] + accB[q*4+2]);
        u.w = bf16rne(accA[q*4+3] + accB[q*4+3]);
        *(ushort4*)&o2[q * 4] = u;
    }
    // register-only stats (no barriers):
    float mc = accA[0], mr = accB[0], m2 = accA[0] + accB[0];
    #pragma unroll
    for (int nn = 1; nn < 32; ++nn) {
        mc = fmaxf(mc, accA[nn]);
        mr = fmaxf(mr, accB[nn]);
        m2 = fmaxf(m2, accA[nn] + accB[nn]);
    }
    const float mcL = mc * LOG2E, mrL = mr * LOG2E, m2L = m2 * LOG2E;
    float sc = 0.f, sr = 0.f, s2 = 0.f;
    #pragma unroll
    for (int nn = 0; nn < 32; ++nn) {
        sc += exp2f(fmaf(accA[nn], LOG2E, -mcL));
        sr += exp2f(fmaf(accB[nn], LOG2E, -mrL));
        s2 += exp2f(fmaf(accA[nn] + accB[nn], LOG2E, -m2L));
    }
    const long sidx = ((long)(b * 128 + j)) * N + m;
    McP[sidx] = mc; ScP[sidx] = sc;
    MrP[sidx] = mr; SrP[sidx] = sr;
    M2P[sidx] = m2; S2P[sidx] = s2;
}

// ---------------------------------------------------------------------------
// Combine 128 partial (max,sumexp) sets -> final stats (+ optional C2L).
// grid: (N/64, B), block 256 = 64 cols x 4 q-groups of 32.
__global__ LB void stats_comb128(const float* __restrict__ Mp, const float* __restrict__ Sp,
                                 float* __restrict__ M, float* __restrict__ Sm,
                                 float* __restrict__ C2L, int N)
{
    __shared__ float lm[4][64], ls[4][64];
    const int c = threadIdx.x & 63, q = threadIdx.x >> 6;
    const int n = blockIdx.x * 64 + c;
    const int b = blockIdx.y;
    float mx = NEG_BIG, sum = 0.f;
    for (int jj = 0; jj < 32; ++jj) {
        const int s = q * 32 + jj;
        online_merge(mx, sum, Mp[((long)(b * 128 + s)) * N + n], Sp[((long)(b * 128 + s)) * N + n]);
    }
    lm[q][c] = mx; ls[q][c] = sum;
    __syncthreads();
    if (q == 0) {
        #pragma unroll
        for (int jj = 1; jj < 4; ++jj) online_merge(mx, sum, lm[jj][c], ls[jj][c]);
        M[(long)b * N + n]  = mx;
        Sm[(long)b * N + n] = sum;
        if (C2L) C2L[(long)b * N + n] = (mx - LN2 + __logf(sum)) * LOG2E;
    }
}

// ---------------------------------------------------------------------------
// MFMA softmax-apply GEMM, K-chunk 64, register prefetch, 4-way K-split.
template<int MROWS>
__global__ LB void sm_gemm_mfma(const ushort* __restrict__ Xbf,
                                const float* __restrict__ A,
                                const float* __restrict__ Mv,
                                float* __restrict__ parts,
                                int N)
{
    constexpr int RT = MROWS / 32;
    constexpr int AR_SH = (MROWS == 128) ? 1 : 2;
    constexpr int ALD = (MROWS == 128) ? 4 : 2;
    __shared__ ushort ldsA[MROWS][80];
    __shared__ ushort ldsB[32][80];

    const int tid = threadIdx.x;
    const int wave = tid >> 6, lane = tid & 63;
    const int col0 = blockIdx.x * 32;
    const int s = blockIdx.y, b = blockIdx.z;
    const int KLEN = N / 4, K0 = s * KLEN;

    const int scol = tid >> 3, sq = tid & 7;
    const int ar = tid >> AR_SH;
    const int ak = (tid & ((1 << AR_SH) - 1)) * (ALD * 8);
    const int wct = wave & 1, wrh = wave >> 1;
    const int fr = lane & 15, fg = lane >> 4;

    f32x4 acc[RT];
    #pragma unroll
    for (int i = 0; i < RT; ++i) acc[i] = (f32x4){0.f, 0.f, 0.f, 0.f};

    const float* ab = A + ((long)b * N + col0) * N + (long)scol * N + K0 + sq * 8;
    const ushort* xb = Xbf + (long)b * MROWS * N + (long)ar * N + K0 + ak;
    const float mvl = Mv[(long)b * N + col0 + scol] * LOG2E;

    float4 bv0 = *(const float4*)&ab[0];
    float4 bv1 = *(const float4*)&ab[4];
    short8v av[ALD];
    #pragma unroll
    for (int j = 0; j < ALD; ++j) av[j] = *(const short8v*)&xb[8 * j];

    const int NIT = KLEN / 64;
    for (int it = 0; it < NIT; ++it) {
        __syncthreads();
        ushort4 o0, o1;
        o0.x = bf16rne(exp2f(fmaf(bv0.x, LOG2E, -mvl)));
        o0.y = bf16rne(exp2f(fmaf(bv0.y, LOG2E, -mvl)));
        o0.z = bf16rne(exp2f(fmaf(bv0.z, LOG2E, -mvl)));
        o0.w = bf16rne(exp2f(fmaf(bv0.w, LOG2E, -mvl)));
        o1.x = bf16rne(exp2f(fmaf(bv1.x, LOG2E, -mvl)));
        o1.y = bf16rne(exp2f(fmaf(bv1.y, LOG2E, -mvl)));
        o1.z = bf16rne(exp2f(fmaf(bv1.z, LOG2E, -mvl)));
        o1.w = bf16rne(exp2f(fmaf(bv1.w, LOG2E, -mvl)));
        *(ushort4*)&ldsB[scol][sq * 8] = o0;
        *(ushort4*)&ldsB[scol][sq * 8 + 4] = o1;
        #pragma unroll
        for (int j = 0; j < ALD; ++j) *(short8v*)&ldsA[ar][ak + 8 * j] = av[j];
        __syncthreads();
        if (it + 1 < NIT) {
            const int kb = (it + 1) * 64;
            bv0 = *(const float4*)&ab[kb];
            bv1 = *(const float4*)&ab[kb + 4];
            #pragma unroll
            for (int j = 0; j < ALD; ++j)
                av[j] = *(const short8v*)&xb[kb + 8 * j];
        }
        #pragma unroll
        for (int kk = 0; kk < 2; ++kk) {
            const short8v bfrag = *(const short8v*)&ldsB[wct * 16 + fr][32 * kk + 8 * fg];
            #pragma unroll
            for (int rt = 0; rt < RT; ++rt) {
                const int row = wrh * (MROWS / 2) + rt * 16 + fr;
                const short8v afrag = *(const short8v*)&ldsA[row][32 * kk + 8 * fg];
                acc[rt] = __builtin_amdgcn_mfma_f32_16x16x32_bf16(afrag, bfrag, acc[rt], 0, 0, 0);
            }
        }
    }

    float* pp = parts + ((long)(s * 2 + b) * MROWS) * N;
    #pragma unroll
    for (int rt = 0; rt < RT; ++rt) {
        #pragma unroll
        for (int r = 0; r < 4; ++r) {
            const int row = wrh * (MROWS / 2) + rt * 16 + fg * 4 + r;
            const int col = col0 + wct * 16 + fr;
            pp[(long)row * N + col] = acc[rt][r];
        }
    }
}

// Sum 4 K-split partials and divide by per-column softmax denom.
template<int C>
__global__ LB void sm_reduce4(const float* __restrict__ parts,
                              const float* __restrict__ denom, float* __restrict__ outp, int N)
{
    const long idx = (long)blockIdx.x * 256 + threadIdx.x;
    const int m = (int)(idx & (long)(N - 1));
    const long bc = idx >> 12;
    const int c = (int)(bc & (C - 1));
    const int b = (int)(bc / C);
    float s = 0.f;
    #pragma unroll
    for (int ss = 0; ss < 4; ++ss)
        s += parts[((long)(ss * 2 + b) * C + c) * N + m];
    outp[idx] = s / denom[(long)b * N + m];
}

// ---------------------------------------------------------------------------
// Fused (single-stream bf16): att3 = exp2(att2*log2e - C2L[x]), 3x3 conv +
// BN + ReLU. Tile 128x32 (halo 130x34). grid: (4096, B).
__global__ LB void attmap_conv(const ushort* __restrict__ att2bf,
                               const float* __restrict__ C2L,
                               const float* __restrict__ w, const float* __restrict__ g,
                               float* __restrict__ out, int N)
{
    __shared__ float tD[34][136];
    __shared__ float ldc[130];
    const int tid = threadIdx.x;
    const int x0 = (blockIdx.x & 31) * 128;
    const int y0 = (blockIdx.x >> 5) * 32;
    const int b = blockIdx.y;
    const ushort* ap = att2bf + (long)b * N * N;
    const float* cp = C2L + (long)b * N;

    if (tid < 130) {
        const int xx = x0 + tid - 1;
        ldc[tid] = ((unsigned)xx < (unsigned)N) ? cp[xx] : 0.f;
    }
    __syncthreads();

    {
        const int xg = (tid & 31) * 4;
        const int rg = tid >> 5;
        #pragma unroll
        for (int i = 0; i < 5; ++i) {
            const int hy = rg + i * 8;
            if (hy < 34) {
                const int yy = y0 + hy - 1;
                float4 v = make_float4(0.f, 0.f, 0.f, 0.f);
                if ((unsigned)yy < (unsigned)N) {
                    const ushort4 a = *(const ushort4*)&ap[(long)yy * N + x0 + xg];
                    v.x = exp2f(fmaf(bf2f(a.x), LOG2E, -ldc[xg + 1]));
                    v.y = exp2f(fmaf(bf2f(a.y), LOG2E, -ldc[xg + 2]));
                    v.z = exp2f(fmaf(bf2f(a.z), LOG2E, -ldc[xg + 3]));
                    v.w = exp2f(fmaf(bf2f(a.w), LOG2E, -ldc[xg + 4]));
                }
                *(float4*)&tD[hy][xg + 4] = v;
            }
        }
    }
    if (tid < 68) {
        const int c01 = tid & 1, hy = tid >> 1;
        const int col = c01 ? 132 : 3;
        const int xx = c01 ? (x0 + 128) : (x0 - 1);
        const int yy = y0 + hy - 1;
        float v = 0.f;
        if ((unsigned)yy < (unsigned)N && (unsigned)xx < (unsigned)N)
            v = exp2f(fmaf(bf2f(ap[(long)yy * N + xx]), LOG2E, -ldc[c01 ? 129 : 0]));
        tD[hy][col] = v;
    }
    __syncthreads();

    const float scale = g[0] * BN_SCALE, beta = g[1];
    const int tx2 = tid & 127, tyg = tid >> 7;
    float* ob = out + (long)b * N * N + (long)y0 * N + x0 + tx2;
    #pragma unroll
    for (int rr = 0; rr < 16; ++rr) {
        const int ly = tyg + rr * 2;
        float acc = 0.f;
        #pragma unroll
        for (int ky = 0; ky < 3; ++ky)
            #pragma unroll
            for (int kx = 0; kx < 3; ++kx)
                acc = fmaf(w[ky * 3 + kx], tD[ly + ky][tx2 + 3 + kx], acc);
        ob[(long)ly * N] = fmaxf(fmaf(acc, scale, beta), 0.f);
    }
}

// ===========================================================================
extern "C" void kernel_launch(void* const* d_in, const int* in_sizes, int n_in,
                              void* d_out, int out_size, void* d_ws, size_t ws_size,
                              hipStream_t stream)
{
    const float* xs   = (const float*)d_in[0];
    const float* xc   = (const float*)d_in[1];
    const float* w_g1 = (const float*)d_in[2];
    const float* g_g1 = (const float*)d_in[3];
    const float* w_g2 = (const float*)d_in[4];
    const float* g_g2 = (const float*)d_in[5];
    const float* w_ls = (const float*)d_in[6];
    const float* b_ls = (const float*)d_in[7];
    const float* g_ls = (const float*)d_in[8];
    const float* w_lc = (const float*)d_in[9];
    const float* b_lc = (const float*)d_in[10];
    const float* g_lc = (const float*)d_in[11];
    const float* w_c1 = (const float*)d_in[12];
    const float* g_c1 = (const float*)d_in[13];
    const float* w_c2 = (const float*)d_in[14];
    const float* g_c2 = (const float*)d_in[15];
    const float* w_o1 = (const float*)d_in[16];
    const float* g_o1 = (const float*)d_in[17];
    const float* w_o2 = (const float*)d_in[18];
    const float* g_o2 = (const float*)d_in[19];
    const float* w_oa = (const float*)d_in[20];
    const float* g_oa = (const float*)d_in[21];

    const int B = 2, HW = 4096, N = 4096;

    // ---- workspace layout (float offsets); high-water ~395MB (<536MB ok) ----
    float* ws = (float*)d_ws;
    float* xs1    = ws;                       // 524288
    float* xc1    = ws + 524288;              // 1048576
    float* fs     = ws + 1572864;             // 262144
    float* fc     = ws + 1835008;             // 262144
    float* t32    = ws + 2097152;             // 262144
    float* outs_w = ws + 2359296;             // 524288
    float* outc_w = ws + 2883584;             // 1048576
    float* gs_w   = ws + 3932160;             // 64
    float* gc_w   = ws + 3932224;             // 64
    float* Mc     = ws + 3932288;             // 8192
    float* Sc     = ws + 3940480;             // 8192
    float* Mr     = ws + 3948672;             // 8192
    float* Sr     = ws + 3956864;             // 8192
    float* M2     = ws + 3965056;             // 8192
    float* S2     = ws + 3973248;             // 8192
    float* C2L    = ws + 3981440;             // 8192
    float* att    = ws + 4243584;             // 33554432
    float* attT   = ws + 37798016;            // 33554432
    float* pg     = ws + 71352448;            // 4x K-split partials (<=16MB)
    ushort* att2bf = (ushort*)(ws + 75546752); // 33554432 ushorts (16.8M fl)
    // stat partials [B,128,N] = 1048576 floats each (after att2bf):
    float* McP    = ws + 92323968;
    float* ScP    = ws + 93372544;
    float* MrP    = ws + 94421120;
    float* SrP    = ws + 95469696;
    float* M2P    = ws + 96518272;
    float* S2P    = ws + 97566848;            // ends 98615424 fl = 394.5MB

    // ---- d_out layout (scratch region [0..33.5M) dead before attmap) ----
    float* out = (float*)d_out;
    float* out_attmap = out;                        // final att_map (LAST write)
    ushort* xs1bf   = (ushort*)out;                 // [0..262144) fl
    ushort* xc1bf   = (ushort*)(out + 262144);      // [262144..786432)
    ushort* xcT     = (ushort*)(out + 786432);      // [786432..1310720)
    ushort* outcT   = (ushort*)(out + 786432);      // reuse after g2/lc
    ushort* xsT     = (ushort*)(out + 1310720);     // [1310720..1572864)
    ushort* outs_wT = (ushort*)(out + 1310720);     // reuse after g1/ls
    ushort* xs1T    = (ushort*)(out + 1572864);     // [1572864..1835008)
    ushort* xc1T    = (ushort*)(out + 1835008);     // [1835008..2359296)
    float* out_s      = out + 33554432;             // 524288
    float* out_c      = out + 34078720;             // 1048576
    float* out_gs     = out + 35127296;             // 64
    float* out_gc     = out + 35127360;             // 64

    const dim3 blk(256);

    // input transposes (bf16)
    transpose_bf<<<dim3(128, 2, B), blk, 0, stream>>>(xs, xsT, 64, HW);
    transpose_bf<<<dim3(128, 4, B), blk, 0, stream>>>(xc, xcT, 128, HW);
    // global context: g1/g2 MFMA convs + GAP
    conv3x3_mfma<0, 32><<<dim3(64, 1, B), blk, 0, stream>>>(xsT, nullptr, w_g1, nullptr, g_g1, nullptr, t32, nullptr, nullptr, 0, 64, 32);
    gap_kernel<<<dim3(32, B), blk, 0, stream>>>(t32, gs_w, out_gs, 32, HW);
    conv3x3_mfma<0, 32><<<dim3(64, 1, B), blk, 0, stream>>>(xcT, nullptr, w_g2, nullptr, g_g2, nullptr, t32, nullptr, nullptr, 0, 128, 32);
    gap_kernel<<<dim3(32, B), blk, 0, stream>>>(t32, gc_w, out_gc, 32, HW);
    // local fusion convs (MFMA, epilogues emit bf16 + transposed copies)
    conv3x3_mfma<1, 64><<<dim3(64, 1, B), blk, 0, stream>>>(xsT, gs_w, w_ls, b_ls, g_ls, xs, xs1, xs1bf, xs1T, 32, 64, 64);
    conv3x3_mfma<1, 64><<<dim3(64, 2, B), blk, 0, stream>>>(xcT, gc_w, w_lc, b_lc, g_lc, xc, xc1, xc1bf, xc1T, 32, 128, 128);
    // attention features (MFMA)
    conv3x3_mfma<0, 32><<<dim3(64, 1, B), blk, 0, stream>>>(xs1T, nullptr, w_c1, nullptr, g_c1, nullptr, fs, nullptr, nullptr, 0, 64, 32);
    conv3x3_mfma<0, 32><<<dim3(64, 1, B), blk, 0, stream>>>(xc1T, nullptr, w_c2, nullptr, g_c2, nullptr, fc, nullptr, nullptr, 0, 128, 32);
    // att GEMM (doubled): att + attT + att2bf + all stat partials
    att_gemm2<<<dim3(16, 128, B), blk, 0, stream>>>(fs, fc, att, attT, att2bf,
                                                    McP, ScP, MrP, SrP, M2P, S2P, N);
    stats_comb128<<<dim3(64, B), blk, 0, stream>>>(McP, ScP, Mc, Sc, nullptr, N);
    stats_comb128<<<dim3(64, B), blk, 0, stream>>>(MrP, SrP, Mr, Sr, nullptr, N);
    stats_comb128<<<dim3(64, B), blk, 0, stream>>>(M2P, S2P, M2, S2, C2L, N);
    // outc = xc1 @ rowsoftmax(att)^T via MFMA; then o2 MFMA conv
    sm_gemm_mfma<128><<<dim3(128, 4, B), blk, 0, stream>>>(xc1bf, att, Mr, pg, N);
    sm_reduce4<128><<<dim3((B * 128 * N) / 256), blk, 0, stream>>>(pg, Sr, outc_w, N);
    transpose_bf<<<dim3(128, 4, B), blk, 0, stream>>>(outc_w, outcT, 128, HW);
    conv3x3_mfma<0, 64><<<dim3(64, 2, B), blk, 0, stream>>>(outcT, nullptr, w_o2, nullptr, g_o2, xc1, out_c, nullptr, nullptr, 0, 128, 128);
    // outs = xs1 @ colsoftmax(att) via MFMA; then o1 MFMA conv
    sm_gemm_mfma<64><<<dim3(128, 4, B), blk, 0, stream>>>(xs1bf, attT, Mc, pg, N);
    sm_reduce4<64><<<dim3((B * 64 * N) / 256), blk, 0, stream>>>(pg, Sc, outs_w, N);
    transpose_bf<<<dim3(128, 2, B), blk, 0, stream>>>(outs_w, outs_wT, 64, HW);
    conv3x3_mfma<0, 64><<<dim3(64, 1, B), blk, 0, stream>>>(outs_wT, nullptr, w_o1, nullptr, g_o1, xs1, out_s, nullptr, nullptr, 0, 64, 64);
    // fused att3+conv LAST (single-stream bf16 att2)
    attmap_conv<<<dim3(4096, B), blk, 0, stream>>>(att2bf, C2L, w_oa, g_oa, out_attmap, N);
}

// Round 23
// 517.982 us; speedup vs baseline: 1.2623x; 1.2623x over previous
//
#include <hip/hip_runtime.h>

// AGLI_5703716569604 — round 22: revert to round-20 best (519us).
// Lean att_gemm; tri_stats emits bf16 att2; single-stream attmap.
// B=2, ch1=64, ch2=128, H=W=64, N=4096, att [B,4096,4096].

#define LB __launch_bounds__(256)

constexpr float BN_SCALE = 0.99999500003749968f; // 1/sqrt(1+1e-5)
constexpr float NEG_BIG  = -3.402823466e38f;
constexpr float LOG2E    = 1.4426950408889634f;
constexpr float LN2      = 0.6931471805599453f;

typedef __attribute__((ext_vector_type(8))) short short8v;
typedef __attribute__((ext_vector_type(4))) float f32x4;

__device__ __forceinline__ ushort bf16rne(float f) {
    unsigned u = __float_as_uint(f);
    unsigned r = (u + 0x7FFFu + ((u >> 16) & 1u)) >> 16;
    return (ushort)r;
}
__device__ __forceinline__ float bf2f(ushort u) {
    return __uint_as_float((unsigned)u << 16);
}

__device__ __forceinline__ void online_merge(float& mx, float& sm, float m2, float s2) {
    const float mn = fmaxf(mx, m2);
    sm = sm * __expf(mx - mn) + s2 * __expf(m2 - mn);
    mx = mn;
}

// ---------------------------------------------------------------------------
// Transpose + bf16: in f32 [B][C][HW] -> outT bf16 [B][HW][C].
__global__ LB void transpose_bf(const float* __restrict__ in, ushort* __restrict__ outT,
                                int C, int HW)
{
    __shared__ float t[32][33];
    const int tid = threadIdx.x;
    const int tx = tid & 31, ty0 = tid >> 5;
    const int hw0 = blockIdx.x * 32, c0 = blockIdx.y * 32, b = blockIdx.z;
    #pragma unroll
    for (int i = 0; i < 4; ++i)
        t[ty0 + i * 8][tx] = in[((long)b * C + c0 + ty0 + i * 8) * HW + hw0 + tx];
    __syncthreads();
    #pragma unroll
    for (int i = 0; i < 4; ++i)
        outT[((long)b * HW + hw0 + ty0 + i * 8) * C + c0 + tx] =
            bf16rne(t[tx][ty0 + i * 8]);
}

// ---------------------------------------------------------------------------
// MFMA direct 3x3 conv (round-18, unchanged).
template<int HASG, int OCB>
__global__ LB void conv3x3_mfma(
    const ushort* __restrict__ inT,
    const float* __restrict__ gconst,
    const float* __restrict__ w,
    const float* __restrict__ bias,
    const float* __restrict__ bn,
    const float* __restrict__ residual,
    float* __restrict__ out,
    ushort* __restrict__ outbf,
    ushort* __restrict__ outTbf,
    int Cg, int Cin, int Cout)
{
    constexpr int TILES = OCB / 16;
    constexpr int TPO = 256 / OCB;
    constexpr int J = 288 / TPO;
    __shared__ ushort ldsA[9][OCB][36];
    __shared__ float wg[OCB][10];
    const int tid = threadIdx.x;
    const int wv = tid >> 6, lane = tid & 63;
    const int fr = lane & 15, fg = lane >> 4;
    const int px0 = blockIdx.x * 64, ocb = blockIdx.y * OCB, b = blockIdx.z;
    const int Ct = Cg + Cin;
    const int p = px0 + wv * 16 + fr;
    const int y = p >> 6, x = p & 63;

    if (HASG) {
        for (int e = tid; e < OCB * 9; e += 256) {
            const int oc = e / 9, k = e % 9;
            float s = 0.f;
            for (int ic = 0; ic < Cg; ++ic)
                s += gconst[b * Cg + ic] * w[((long)(ocb + oc) * Ct + ic) * 9 + k];
            wg[oc][k] = s;
        }
    }

    int qv[9]; bool val[9];
    #pragma unroll
    for (int k = 0; k < 9; ++k) {
        const int yy = y + k / 3 - 1, xx = x + k % 3 - 1;
        val[k] = ((unsigned)yy < 64u) && ((unsigned)xx < 64u);
        qv[k] = val[k] ? (yy * 64 + xx) : 0;
    }

    f32x4 acc[TILES];
    #pragma unroll
    for (int t = 0; t < TILES; ++t) acc[t] = (f32x4){0.f, 0.f, 0.f, 0.f};
    const short8v bz = (short8v){0, 0, 0, 0, 0, 0, 0, 0};

    const int oc_st = tid / TPO, q = tid % TPO;
    const int base_ic = q * (J / 9);
    const ushort* inTb = inT + (long)b * 4096 * Cin + 8 * fg;

    const int NCH = Cin / 32;
    for (int c = 0; c < NCH; ++c) {
        __syncthreads();
        {
            const float* wp = w + (long)(ocb + oc_st) * Ct * 9
                              + (long)(Cg + c * 32) * 9 + q * J;
            #pragma unroll
            for (int j4 = 0; j4 < J; j4 += 4) {
                const float4 v4 = *(const float4*)&wp[j4];
                ldsA[(j4 + 0) % 9][oc_st][base_ic + (j4 + 0) / 9] = bf16rne(v4.x);
                ldsA[(j4 + 1) % 9][oc_st][base_ic + (j4 + 1) / 9] = bf16rne(v4.y);
                ldsA[(j4 + 2) % 9][oc_st][base_ic + (j4 + 2) / 9] = bf16rne(v4.z);
                ldsA[(j4 + 3) % 9][oc_st][base_ic + (j4 + 3) / 9] = bf16rne(v4.w);
            }
        }
        __syncthreads();
        const ushort* inc = inTb + c * 32;
        #pragma unroll
        for (int k = 0; k < 9; ++k) {
            const short8v bfrag = val[k] ? *(const short8v*)&inc[(long)qv[k] * Cin] : bz;
            #pragma unroll
            for (int t = 0; t < TILES; ++t) {
                const short8v afrag = *(const short8v*)&ldsA[k][t * 16 + fr][8 * fg];
                acc[t] = __builtin_amdgcn_mfma_f32_16x16x32_bf16(afrag, bfrag, acc[t], 0, 0, 0);
            }
        }
    }

    #pragma unroll
    for (int t = 0; t < TILES; ++t) {
        float v4[4];
        #pragma unroll
        for (int r = 0; r < 4; ++r) {
            const int ocl = t * 16 + fg * 4 + r;
            const int oc = ocb + ocl;
            float v = acc[t][r];
            if (bias) v += bias[oc];
            if (HASG) {
                #pragma unroll
                for (int k = 0; k < 9; ++k)
                    if (val[k]) v += wg[ocl][k];
            }
            v = fmaxf(fmaf(v, bn[oc] * BN_SCALE, bn[Cout + oc]), 0.f);
            const long oidx = ((long)(b * Cout + oc)) * 4096 + p;
            if (residual) v += residual[oidx];
            out[oidx] = v;
            if (outbf) outbf[oidx] = bf16rne(v);
            v4[r] = v;
        }
        if (outTbf) {
            ushort4 o;
            o.x = bf16rne(v4[0]); o.y = bf16rne(v4[1]);
            o.z = bf16rne(v4[2]); o.w = bf16rne(v4[3]);
            *(ushort4*)&outTbf[((long)(b * 4096 + p)) * Cout + ocb + t * 16 + fg * 4] = o;
        }
    }
}

// ---------------------------------------------------------------------------
__global__ LB void gap_kernel(const float* __restrict__ in,
                              float* __restrict__ o1, float* __restrict__ o2,
                              int C, int HW)
{
    const int c = blockIdx.x, b = blockIdx.y;
    const float* p = in + ((long)b * C + c) * HW;
    float s = 0.f;
    for (int i = threadIdx.x; i < HW; i += 256) s += p[i];
    #pragma unroll
    for (int off = 32; off; off >>= 1) s += __shfl_down(s, off);
    __shared__ float red[4];
    if ((threadIdx.x & 63) == 0) red[threadIdx.x >> 6] = s;
    __syncthreads();
    if (threadIdx.x == 0) {
        const float t = (red[0] + red[1] + red[2] + red[3]) / (float)HW;
        o1[b * C + c] = t;
        o2[b * C + c] = t;
    }
}

// ---------------------------------------------------------------------------
// att[b,n,m] = sum_c fs[b,c,n] * fc[b,c,m], C=32. Also writes attT[b,m,n].
__global__ LB void att_gemm(const float* __restrict__ fs, const float* __restrict__ fc,
                            float* __restrict__ att, float* __restrict__ attT, int N)
{
    __shared__ float lfs[32][33];
    const int tid = threadIdx.x;
    const int m  = blockIdx.x * 256 + tid;
    const int n0 = blockIdx.y * 32;
    const int b  = blockIdx.z;
    for (int i = tid; i < 1024; i += 256) {
        const int c = i >> 5, nn = i & 31;
        lfs[c][nn] = fs[((long)b * 32 + c) * N + n0 + nn];
    }
    __syncthreads();
    float acc[32];
    #pragma unroll
    for (int i = 0; i < 32; ++i) acc[i] = 0.f;
    const float* fcp = fc + (long)b * 32 * N + m;
    #pragma unroll
    for (int c = 0; c < 32; ++c) {
        const float f = fcp[(long)c * N];
        #pragma unroll
        for (int nn = 0; nn < 32; ++nn) acc[nn] = fmaf(lfs[c][nn], f, acc[nn]);
    }
    float* op = att + ((long)b * N + n0) * N + m;
    #pragma unroll
    for (int nn = 0; nn < 32; ++nn) op[(long)nn * N] = acc[nn];
    float* opT = attT + ((long)b * N + m) * N + n0;
    #pragma unroll
    for (int q = 0; q < 8; ++q)
        *(float4*)&opT[q * 4] = make_float4(acc[q*4], acc[q*4+1], acc[q*4+2], acc[q*4+3]);
}

// ---------------------------------------------------------------------------
// ONE streaming pass over att+attT: 3 stat partial sets [B,32,N] + bf16 att2.
__global__ LB void tri_stats(const float* __restrict__ att, const float* __restrict__ attT,
                             ushort* __restrict__ att2bf,
                             float* __restrict__ McP, float* __restrict__ ScP,
                             float* __restrict__ MrP, float* __restrict__ SrP,
                             float* __restrict__ M2P, float* __restrict__ S2P, int N)
{
    __shared__ float lm[3][4][64], ls[3][4][64];
    const int c = threadIdx.x & 63, q = threadIdx.x >> 6;
    const int m = blockIdx.x * 64 + c;
    const int y = blockIdx.y, b = blockIdx.z;
    const long base = (long)b * N * N + ((long)y * 128 + q) * N + m;

    float av[32], tv[32];
    #pragma unroll
    for (int r = 0; r < 32; ++r) {
        const long off = base + (long)r * 4 * N;
        av[r] = att[off];
        tv[r] = attT[off];
        att2bf[off] = bf16rne(av[r] + tv[r]);
    }
    float mc = av[0], mr = tv[0], m2 = av[0] + tv[0];
    #pragma unroll
    for (int r = 1; r < 32; ++r) {
        mc = fmaxf(mc, av[r]);
        mr = fmaxf(mr, tv[r]);
        m2 = fmaxf(m2, av[r] + tv[r]);
    }
    const float mcL = mc * LOG2E, mrL = mr * LOG2E, m2L = m2 * LOG2E;
    float sc = 0.f, sr = 0.f, s2 = 0.f;
    #pragma unroll
    for (int r = 0; r < 32; ++r) {
        sc += exp2f(fmaf(av[r], LOG2E, -mcL));
        sr += exp2f(fmaf(tv[r], LOG2E, -mrL));
        s2 += exp2f(fmaf(av[r] + tv[r], LOG2E, -m2L));
    }

    lm[0][q][c] = mc; ls[0][q][c] = sc;
    lm[1][q][c] = mr; ls[1][q][c] = sr;
    lm[2][q][c] = m2; ls[2][q][c] = s2;
    __syncthreads();
    if (q < 3) {
        float M = lm[q][0][c], S = ls[q][0][c];
        #pragma unroll
        for (int j = 1; j < 4; ++j) online_merge(M, S, lm[q][j][c], ls[q][j][c]);
        float* Pm = (q == 0) ? McP : ((q == 1) ? MrP : M2P);
        float* Ps = (q == 0) ? ScP : ((q == 1) ? SrP : S2P);
        Pm[((long)(b * 32 + y)) * N + m] = M;
        Ps[((long)(b * 32 + y)) * N + m] = S;
    }
}

// ---------------------------------------------------------------------------
// Combine 32 partial (max,sumexp) sets -> final stats (+ optional C2L).
__global__ LB void stats_comb32(const float* __restrict__ Mp, const float* __restrict__ Sp,
                                float* __restrict__ M, float* __restrict__ Sm,
                                float* __restrict__ C2L, int N)
{
    __shared__ float lm[4][64], ls[4][64];
    const int c = threadIdx.x & 63, q = threadIdx.x >> 6;
    const int n = blockIdx.x * 64 + c;
    const int b = blockIdx.y;
    float mx = NEG_BIG, sum = 0.f;
    #pragma unroll
    for (int j = 0; j < 8; ++j) {
        const int s = q * 8 + j;
        online_merge(mx, sum, Mp[((long)(b * 32 + s)) * N + n], Sp[((long)(b * 32 + s)) * N + n]);
    }
    lm[q][c] = mx; ls[q][c] = sum;
    __syncthreads();
    if (q == 0) {
        #pragma unroll
        for (int j = 1; j < 4; ++j) online_merge(mx, sum, lm[j][c], ls[j][c]);
        M[(long)b * N + n]  = mx;
        Sm[(long)b * N + n] = sum;
        if (C2L) C2L[(long)b * N + n] = (mx - LN2 + __logf(sum)) * LOG2E;
    }
}

// ---------------------------------------------------------------------------
// MFMA softmax-apply GEMM, K-chunk 64, register prefetch, 4-way K-split.
template<int MROWS>
__global__ LB void sm_gemm_mfma(const ushort* __restrict__ Xbf,
                                const float* __restrict__ A,
                                const float* __restrict__ Mv,
                                float* __restrict__ parts,
                                int N)
{
    constexpr int RT = MROWS / 32;
    constexpr int AR_SH = (MROWS == 128) ? 1 : 2;
    constexpr int ALD = (MROWS == 128) ? 4 : 2;
    __shared__ ushort ldsA[MROWS][80];
    __shared__ ushort ldsB[32][80];

    const int tid = threadIdx.x;
    const int wave = tid >> 6, lane = tid & 63;
    const int col0 = blockIdx.x * 32;
    const int s = blockIdx.y, b = blockIdx.z;
    const int KLEN = N / 4, K0 = s * KLEN;

    const int scol = tid >> 3, sq = tid & 7;
    const int ar = tid >> AR_SH;
    const int ak = (tid & ((1 << AR_SH) - 1)) * (ALD * 8);
    const int wct = wave & 1, wrh = wave >> 1;
    const int fr = lane & 15, fg = lane >> 4;

    f32x4 acc[RT];
    #pragma unroll
    for (int i = 0; i < RT; ++i) acc[i] = (f32x4){0.f, 0.f, 0.f, 0.f};

    const float* ab = A + ((long)b * N + col0) * N + (long)scol * N + K0 + sq * 8;
    const ushort* xb = Xbf + (long)b * MROWS * N + (long)ar * N + K0 + ak;
    const float mvl = Mv[(long)b * N + col0 + scol] * LOG2E;

    float4 bv0 = *(const float4*)&ab[0];
    float4 bv1 = *(const float4*)&ab[4];
    short8v av[ALD];
    #pragma unroll
    for (int j = 0; j < ALD; ++j) av[j] = *(const short8v*)&xb[8 * j];

    const int NIT = KLEN / 64;
    for (int it = 0; it < NIT; ++it) {
        __syncthreads();
        ushort4 o0, o1;
        o0.x = bf16rne(exp2f(fmaf(bv0.x, LOG2E, -mvl)));
        o0.y = bf16rne(exp2f(fmaf(bv0.y, LOG2E, -mvl)));
        o0.z = bf16rne(exp2f(fmaf(bv0.z, LOG2E, -mvl)));
        o0.w = bf16rne(exp2f(fmaf(bv0.w, LOG2E, -mvl)));
        o1.x = bf16rne(exp2f(fmaf(bv1.x, LOG2E, -mvl)));
        o1.y = bf16rne(exp2f(fmaf(bv1.y, LOG2E, -mvl)));
        o1.z = bf16rne(exp2f(fmaf(bv1.z, LOG2E, -mvl)));
        o1.w = bf16rne(exp2f(fmaf(bv1.w, LOG2E, -mvl)));
        *(ushort4*)&ldsB[scol][sq * 8] = o0;
        *(ushort4*)&ldsB[scol][sq * 8 + 4] = o1;
        #pragma unroll
        for (int j = 0; j < ALD; ++j) *(short8v*)&ldsA[ar][ak + 8 * j] = av[j];
        __syncthreads();
        if (it + 1 < NIT) {
            const int kb = (it + 1) * 64;
            bv0 = *(const float4*)&ab[kb];
            bv1 = *(const float4*)&ab[kb + 4];
            #pragma unroll
            for (int j = 0; j < ALD; ++j)
                av[j] = *(const short8v*)&xb[kb + 8 * j];
        }
        #pragma unroll
        for (int kk = 0; kk < 2; ++kk) {
            const short8v bfrag = *(const short8v*)&ldsB[wct * 16 + fr][32 * kk + 8 * fg];
            #pragma unroll
            for (int rt = 0; rt < RT; ++rt) {
                const int row = wrh * (MROWS / 2) + rt * 16 + fr;
                const short8v afrag = *(const short8v*)&ldsA[row][32 * kk + 8 * fg];
                acc[rt] = __builtin_amdgcn_mfma_f32_16x16x32_bf16(afrag, bfrag, acc[rt], 0, 0, 0);
            }
        }
    }

    float* pp = parts + ((long)(s * 2 + b) * MROWS) * N;
    #pragma unroll
    for (int rt = 0; rt < RT; ++rt) {
        #pragma unroll
        for (int r = 0; r < 4; ++r) {
            const int row = wrh * (MROWS / 2) + rt * 16 + fg * 4 + r;
            const int col = col0 + wct * 16 + fr;
            pp[(long)row * N + col] = acc[rt][r];
        }
    }
}

// Sum 4 K-split partials and divide by per-column softmax denom.
template<int C>
__global__ LB void sm_reduce4(const float* __restrict__ parts,
                              const float* __restrict__ denom, float* __restrict__ outp, int N)
{
    const long idx = (long)blockIdx.x * 256 + threadIdx.x;
    const int m = (int)(idx & (long)(N - 1));
    const long bc = idx >> 12;
    const int c = (int)(bc & (C - 1));
    const int b = (int)(bc / C);
    float s = 0.f;
    #pragma unroll
    for (int ss = 0; ss < 4; ++ss)
        s += parts[((long)(ss * 2 + b) * C + c) * N + m];
    outp[idx] = s / denom[(long)b * N + m];
}

// ---------------------------------------------------------------------------
// Fused (single-stream bf16): att3 = exp2(att2*log2e - C2L[x]), 3x3 conv +
// BN + ReLU. Tile 128x32 (halo 130x34). grid: (4096, B).
__global__ LB void attmap_conv(const ushort* __restrict__ att2bf,
                               const float* __restrict__ C2L,
                               const float* __restrict__ w, const float* __restrict__ g,
                               float* __restrict__ out, int N)
{
    __shared__ float tD[34][136];
    __shared__ float ldc[130];
    const int tid = threadIdx.x;
    const int x0 = (blockIdx.x & 31) * 128;
    const int y0 = (blockIdx.x >> 5) * 32;
    const int b = blockIdx.y;
    const ushort* ap = att2bf + (long)b * N * N;
    const float* cp = C2L + (long)b * N;

    if (tid < 130) {
        const int xx = x0 + tid - 1;
        ldc[tid] = ((unsigned)xx < (unsigned)N) ? cp[xx] : 0.f;
    }
    __syncthreads();

    {
        const int xg = (tid & 31) * 4;
        const int rg = tid >> 5;
        #pragma unroll
        for (int i = 0; i < 5; ++i) {
            const int hy = rg + i * 8;
            if (hy < 34) {
                const int yy = y0 + hy - 1;
                float4 v = make_float4(0.f, 0.f, 0.f, 0.f);
                if ((unsigned)yy < (unsigned)N) {
                    const ushort4 a = *(const ushort4*)&ap[(long)yy * N + x0 + xg];
                    v.x = exp2f(fmaf(bf2f(a.x), LOG2E, -ldc[xg + 1]));
                    v.y = exp2f(fmaf(bf2f(a.y), LOG2E, -ldc[xg + 2]));
                    v.z = exp2f(fmaf(bf2f(a.z), LOG2E, -ldc[xg + 3]));
                    v.w = exp2f(fmaf(bf2f(a.w), LOG2E, -ldc[xg + 4]));
                }
                *(float4*)&tD[hy][xg + 4] = v;
            }
        }
    }
    if (tid < 68) {
        const int c01 = tid & 1, hy = tid >> 1;
        const int col = c01 ? 132 : 3;
        const int xx = c01 ? (x0 + 128) : (x0 - 1);
        const int yy = y0 + hy - 1;
        float v = 0.f;
        if ((unsigned)yy < (unsigned)N && (unsigned)xx < (unsigned)N)
            v = exp2f(fmaf(bf2f(ap[(long)yy * N + xx]), LOG2E, -ldc[c01 ? 129 : 0]));
        tD[hy][col] = v;
    }
    __syncthreads();

    const float scale = g[0] * BN_SCALE, beta = g[1];
    const int tx2 = tid & 127, tyg = tid >> 7;
    float* ob = out + (long)b * N * N + (long)y0 * N + x0 + tx2;
    #pragma unroll
    for (int rr = 0; rr < 16; ++rr) {
        const int ly = tyg + rr * 2;
        float acc = 0.f;
        #pragma unroll
        for (int ky = 0; ky < 3; ++ky)
            #pragma unroll
            for (int kx = 0; kx < 3; ++kx)
                acc = fmaf(w[ky * 3 + kx], tD[ly + ky][tx2 + 3 + kx], acc);
        ob[(long)ly * N] = fmaxf(fmaf(acc, scale, beta), 0.f);
    }
}

// ===========================================================================
extern "C" void kernel_launch(void* const* d_in, const int* in_sizes, int n_in,
                              void* d_out, int out_size, void* d_ws, size_t ws_size,
                              hipStream_t stream)
{
    const float* xs   = (const float*)d_in[0];
    const float* xc   = (const float*)d_in[1];
    const float* w_g1 = (const float*)d_in[2];
    const float* g_g1 = (const float*)d_in[3];
    const float* w_g2 = (const float*)d_in[4];
    const float* g_g2 = (const float*)d_in[5];
    const float* w_ls = (const float*)d_in[6];
    const float* b_ls = (const float*)d_in[7];
    const float* g_ls = (const float*)d_in[8];
    const float* w_lc = (const float*)d_in[9];
    const float* b_lc = (const float*)d_in[10];
    const float* g_lc = (const float*)d_in[11];
    const float* w_c1 = (const float*)d_in[12];
    const float* g_c1 = (const float*)d_in[13];
    const float* w_c2 = (const float*)d_in[14];
    const float* g_c2 = (const float*)d_in[15];
    const float* w_o1 = (const float*)d_in[16];
    const float* g_o1 = (const float*)d_in[17];
    const float* w_o2 = (const float*)d_in[18];
    const float* g_o2 = (const float*)d_in[19];
    const float* w_oa = (const float*)d_in[20];
    const float* g_oa = (const float*)d_in[21];

    const int B = 2, HW = 4096, N = 4096;

    // ---- workspace layout (float offsets); high-water ~336MB (<536MB ok) ----
    float* ws = (float*)d_ws;
    float* xs1    = ws;                       // 524288
    float* xc1    = ws + 524288;              // 1048576
    float* fs     = ws + 1572864;             // 262144
    float* fc     = ws + 1835008;             // 262144
    float* t32    = ws + 2097152;             // 262144
    float* McP    = ws + 1572864;             // stat partials (after att_gemm)
    float* ScP    = ws + 1835008;
    float* MrP    = ws + 2097152;
    float* SrP    = ws + 2359296;
    float* M2P    = ws + 2621440;
    float* S2P    = ws + 2883584;
    float* outs_w = ws + 2359296;             // 524288
    float* outc_w = ws + 2883584;             // 1048576
    float* gs_w   = ws + 3932160;             // 64
    float* gc_w   = ws + 3932224;             // 64
    float* Mc     = ws + 3932288;             // 8192
    float* Sc     = ws + 3940480;             // 8192
    float* Mr     = ws + 3948672;             // 8192
    float* Sr     = ws + 3956864;             // 8192
    float* M2     = ws + 3965056;             // 8192
    float* S2     = ws + 3973248;             // 8192
    float* C2L    = ws + 3981440;             // 8192
    float* att    = ws + 4243584;             // 33554432
    float* attT   = ws + 37798016;            // 33554432
    float* pg     = ws + 71352448;            // 4x K-split partials (<=16MB)
    ushort* att2bf = (ushort*)(ws + 75546752); // 33554432 ushorts (67MB)

    // ---- d_out layout (scratch region [0..33.5M) dead before attmap) ----
    float* out = (float*)d_out;
    float* out_attmap = out;                        // final att_map (LAST write)
    ushort* xs1bf   = (ushort*)out;                 // [0..262144) fl
    ushort* xc1bf   = (ushort*)(out + 262144);      // [262144..786432)
    ushort* xcT     = (ushort*)(out + 786432);      // [786432..1310720)
    ushort* outcT   = (ushort*)(out + 786432);      // reuse after g2/lc
    ushort* xsT     = (ushort*)(out + 1310720);     // [1310720..1572864)
    ushort* outs_wT = (ushort*)(out + 1310720);     // reuse after g1/ls
    ushort* xs1T    = (ushort*)(out + 1572864);     // [1572864..1835008)
    ushort* xc1T    = (ushort*)(out + 1835008);     // [1835008..2359296)
    float* out_s      = out + 33554432;             // 524288
    float* out_c      = out + 34078720;             // 1048576
    float* out_gs     = out + 35127296;             // 64
    float* out_gc     = out + 35127360;             // 64

    const dim3 blk(256);

    // input transposes (bf16)
    transpose_bf<<<dim3(128, 2, B), blk, 0, stream>>>(xs, xsT, 64, HW);
    transpose_bf<<<dim3(128, 4, B), blk, 0, stream>>>(xc, xcT, 128, HW);
    // global context: g1/g2 MFMA convs + GAP
    conv3x3_mfma<0, 32><<<dim3(64, 1, B), blk, 0, stream>>>(xsT, nullptr, w_g1, nullptr, g_g1, nullptr, t32, nullptr, nullptr, 0, 64, 32);
    gap_kernel<<<dim3(32, B), blk, 0, stream>>>(t32, gs_w, out_gs, 32, HW);
    conv3x3_mfma<0, 32><<<dim3(64, 1, B), blk, 0, stream>>>(xcT, nullptr, w_g2, nullptr, g_g2, nullptr, t32, nullptr, nullptr, 0, 128, 32);
    gap_kernel<<<dim3(32, B), blk, 0, stream>>>(t32, gc_w, out_gc, 32, HW);
    // local fusion convs (MFMA, epilogues emit bf16 + transposed copies)
    conv3x3_mfma<1, 64><<<dim3(64, 1, B), blk, 0, stream>>>(xsT, gs_w, w_ls, b_ls, g_ls, xs, xs1, xs1bf, xs1T, 32, 64, 64);
    conv3x3_mfma<1, 64><<<dim3(64, 2, B), blk, 0, stream>>>(xcT, gc_w, w_lc, b_lc, g_lc, xc, xc1, xc1bf, xc1T, 32, 128, 128);
    // attention features (MFMA)
    conv3x3_mfma<0, 32><<<dim3(64, 1, B), blk, 0, stream>>>(xs1T, nullptr, w_c1, nullptr, g_c1, nullptr, fs, nullptr, nullptr, 0, 64, 32);
    conv3x3_mfma<0, 32><<<dim3(64, 1, B), blk, 0, stream>>>(xc1T, nullptr, w_c2, nullptr, g_c2, nullptr, fc, nullptr, nullptr, 0, 128, 32);
    // att = fs^T fc  (+ attT, both in ws)
    att_gemm<<<dim3(16, 128, B), blk, 0, stream>>>(fs, fc, att, attT, N);
    // stats (+ bf16 att2 materialization) + combines
    tri_stats<<<dim3(64, 32, B), blk, 0, stream>>>(att, attT, att2bf, McP, ScP, MrP, SrP, M2P, S2P, N);
    stats_comb32<<<dim3(64, B), blk, 0, stream>>>(McP, ScP, Mc, Sc, nullptr, N);
    stats_comb32<<<dim3(64, B), blk, 0, stream>>>(MrP, SrP, Mr, Sr, nullptr, N);
    stats_comb32<<<dim3(64, B), blk, 0, stream>>>(M2P, S2P, M2, S2, C2L, N);
    // outc = xc1 @ rowsoftmax(att)^T via MFMA; then o2 MFMA conv
    sm_gemm_mfma<128><<<dim3(128, 4, B), blk, 0, stream>>>(xc1bf, att, Mr, pg, N);
    sm_reduce4<128><<<dim3((B * 128 * N) / 256), blk, 0, stream>>>(pg, Sr, outc_w, N);
    transpose_bf<<<dim3(128, 4, B), blk, 0, stream>>>(outc_w, outcT, 128, HW);
    conv3x3_mfma<0, 64><<<dim3(64, 2, B), blk, 0, stream>>>(outcT, nullptr, w_o2, nullptr, g_o2, xc1, out_c, nullptr, nullptr, 0, 128, 128);
    // outs = xs1 @ colsoftmax(att) via MFMA; then o1 MFMA conv
    sm_gemm_mfma<64><<<dim3(128, 4, B), blk, 0, stream>>>(xs1bf, attT, Mc, pg, N);
    sm_reduce4<64><<<dim3((B * 64 * N) / 256), blk, 0, stream>>>(pg, Sc, outs_w, N);
    transpose_bf<<<dim3(128, 2, B), blk, 0, stream>>>(outs_w, outs_wT, 64, HW);
    conv3x3_mfma<0, 64><<<dim3(64, 1, B), blk, 0, stream>>>(outs_wT, nullptr, w_o1, nullptr, g_o1, xs1, out_s, nullptr, nullptr, 0, 64, 64);
    // fused att3+conv LAST (single-stream bf16 att2)
    attmap_conv<<<dim3(4096, B), blk, 0, stream>>>(att2bf, C2L, w_oa, g_oa, out_attmap, N);
}